// Round 2
// baseline (546.256 us; speedup 1.0000x reference)
//
#include <hip/hip_runtime.h>
#include <stdint.h>

// DCNv2 x3 for MI355X. fp32 I/O (per reference), fp16 internal + MFMA f16.
// B=4, H=W=96. Layers: (64->64), (64->512), (512->256).

#define HH 96
#define WW 96
#define BBATCH 4
#define HWP (HH*WW)        // 9216
#define PTOT (BBATCH*HWP)  // 36864

typedef _Float16 f16x8 __attribute__((ext_vector_type(8)));
typedef float f32x4 __attribute__((ext_vector_type(4)));

union U16x8 { uint4 q; _Float16 h[8]; };

// ---- NCHW(f32, C=64) -> NHWC(f16) ----
__global__ void k_nchw2nhwc(const float* __restrict__ in, _Float16* __restrict__ out){
  __shared__ float t[32][33];
  int b = blockIdx.z;
  int p0 = blockIdx.x*32, c0 = blockIdx.y*32;
  int tx = threadIdx.x, ty = threadIdx.y; // 32x8
  #pragma unroll
  for(int i=0;i<32;i+=8){
    t[ty+i][tx] = in[((size_t)(b*64 + c0+ty+i))*HWP + p0+tx];
  }
  __syncthreads();
  #pragma unroll
  for(int i=0;i<32;i+=8){
    out[((size_t)(b*HWP + p0+ty+i))*64 + c0+tx] = (_Float16)t[tx][ty+i];
  }
}

// ---- ow [27][CIN][3][3] f32 -> owT [9][32][CIN] f16, rows 27..31 zero ----
template<int CIN>
__global__ void k_tow(const float* __restrict__ ow, _Float16* __restrict__ owT){
  int i = blockIdx.x*256 + threadIdx.x;
  if(i >= 9*32*CIN) return;
  int c = i % CIN; int j = (i/CIN)&31; int k = i/(CIN*32);
  owT[i] = (j<27) ? (_Float16)ow[((size_t)(j*CIN + c))*9 + k] : (_Float16)0.f;
}

// ---- w [COUT][CIN][3][3] f32 -> wT [9][COUT][CIN] f16 ----
template<int CIN,int COUT>
__global__ void k_tw(const float* __restrict__ w, _Float16* __restrict__ wT){
  int i = blockIdx.x*256 + threadIdx.x;
  if(i >= 9*COUT*CIN) return;
  int c = i % CIN; int o = (i/CIN)%COUT; int k = i/(CIN*COUT);
  wT[i] = (_Float16)w[((size_t)(o*CIN + c))*9 + k];
}

// ---- offset conv GEMM: om[P][32] = sum_{k,c} in[p+dk][c] * owT[k][j][c] ----
template<int CIN>
__launch_bounds__(256,2)
__global__ void k_goffs(const _Float16* __restrict__ xin, const _Float16* __restrict__ owT,
                        float* __restrict__ om){
  __shared__ __align__(16) _Float16 As[64*40];
  __shared__ __align__(16) _Float16 Bs[32*40];
  int pos0 = blockIdx.x*64;
  int t = threadIdx.x;
  int lane = t&63, wave = t>>6;
  int quad = lane>>4, l15 = lane&15;
  f32x4 acc[2] = {};
  int pa = t>>2, ca = (t&3)*8;
  int P = pos0 + pa;
  int b = P/HWP, rem = P%HWP;
  int y = rem/WW, x = rem%WW;
  #pragma unroll 1
  for(int k=0;k<9;k++){
    int iy = y + k/3 - 1, ix = x + k%3 - 1;
    bool valid = (iy>=0)&&(iy<HH)&&(ix>=0)&&(ix<WW);
    const _Float16* src = xin + (((size_t)b*HWP + iy*WW + ix)*CIN) + ca;
    #pragma unroll 1
    for(int c0=0;c0<CIN;c0+=32){
      uint4 av = make_uint4(0,0,0,0);
      if(valid) av = *(const uint4*)(src + c0);
      *(uint4*)&As[pa*40 + ca] = av;
      if(t < 128){
        int j = t>>2;
        *(uint4*)&Bs[j*40 + ca] = *(const uint4*)(owT + ((size_t)k*32 + j)*CIN + c0 + ca);
      }
      __syncthreads();
      f16x8 af = *(const f16x8*)&As[(wave*16 + l15)*40 + quad*8];
      #pragma unroll
      for(int ni=0;ni<2;ni++){
        f16x8 bfv = *(const f16x8*)&Bs[(ni*16 + l15)*40 + quad*8];
        acc[ni] = __builtin_amdgcn_mfma_f32_16x16x32_f16(af, bfv, acc[ni], 0,0,0);
      }
      __syncthreads();
    }
  }
  #pragma unroll
  for(int ni=0;ni<2;ni++)
    #pragma unroll
    for(int r=0;r<4;r++){
      int row = wave*16 + quad*4 + r;
      om[(size_t)(pos0+row)*32 + ni*16 + l15] = acc[ni][r];
    }
}

// ---- per-(p,k) sampling params: py, px, mask ----
__global__ void k_prep(const float* __restrict__ om, const float* __restrict__ ob,
                       float* __restrict__ pym){
  int i = blockIdx.x*256 + threadIdx.x;
  if(i >= PTOT*9) return;
  int k = i%9, p = i/9;
  int rem = p%HWP;
  int y = rem/WW, x = rem%WW;
  const float* o = om + (size_t)p*32;
  float oy = o[2*k]   + ob[2*k];
  float ox = o[2*k+1] + ob[2*k+1];
  float mm = o[18+k]  + ob[18+k];
  float m = 1.f/(1.f + expf(-mm));
  pym[(size_t)i*3+0] = (float)(y + k/3 - 1) + oy;
  pym[(size_t)i*3+1] = (float)(x + k%3 - 1) + ox;
  pym[(size_t)i*3+2] = m;
}

// ---- main DCN GEMM: out[p][o] = bias[o] + sum_{k,c} samp_k(p,c) * wT[k][o][c] ----
// 64 x BN tile, 4 waves split N. FINAL: write fp32 NCHW, else f16 NHWC.
template<int CIN,int COUT,int BN,int FINAL>
__launch_bounds__(256,2)
__global__ void k_gmain(const _Float16* __restrict__ xin, const float* __restrict__ pym,
                        const _Float16* __restrict__ wT, const float* __restrict__ bias,
                        void* __restrict__ outv){
  constexpr int NW = BN/4;      // per-wave N width
  constexpr int NF = NW/16;     // n-frags per wave
  __shared__ __align__(16) _Float16 As[64*40];
  __shared__ __align__(16) _Float16 Bs[BN*40];
  int pos0 = blockIdx.x*64;
  int o0 = blockIdx.y*BN;
  int t = threadIdx.x;
  int lane = t&63, wave = t>>6;
  int quad = lane>>4, l15 = lane&15;
  f32x4 acc[4][NF] = {};
  int pa = t>>2, ca = (t&3)*8;
  int P = pos0 + pa;
  int b = P/HWP;
  const _Float16* base = xin + (size_t)b*HWP*CIN;
  #pragma unroll 1
  for(int k=0;k<9;k++){
    const float* pp = pym + ((size_t)P*9 + k)*3;
    float py = pp[0], px = pp[1], mk = pp[2];
    float y0f = floorf(py), x0f = floorf(px);
    float wy = py - y0f, wx = px - x0f;
    int iy0 = (int)y0f, ix0 = (int)x0f;
    int iy1 = iy0+1, ix1 = ix0+1;
    bool vy0 = (iy0>=0)&&(iy0<HH), vy1 = (iy1>=0)&&(iy1<HH);
    bool vx0 = (ix0>=0)&&(ix0<WW), vx1 = (ix1>=0)&&(ix1<WW);
    float w00 = (vy0&&vx0) ? (1.f-wy)*(1.f-wx)*mk : 0.f;
    float w01 = (vy0&&vx1) ? (1.f-wy)*wx*mk      : 0.f;
    float w10 = (vy1&&vx0) ? wy*(1.f-wx)*mk      : 0.f;
    float w11 = (vy1&&vx1) ? wy*wx*mk            : 0.f;
    int cy0 = min(max(iy0,0),HH-1), cy1 = min(max(iy1,0),HH-1);
    int cx0 = min(max(ix0,0),WW-1), cx1 = min(max(ix1,0),WW-1);
    const _Float16* p00 = base + ((size_t)(cy0*WW+cx0))*CIN + ca;
    const _Float16* p01 = base + ((size_t)(cy0*WW+cx1))*CIN + ca;
    const _Float16* p10 = base + ((size_t)(cy1*WW+cx0))*CIN + ca;
    const _Float16* p11 = base + ((size_t)(cy1*WW+cx1))*CIN + ca;
    const _Float16* wkb = wT + ((size_t)k*COUT + o0)*CIN;
    #pragma unroll 1
    for(int c0=0;c0<CIN;c0+=32){
      U16x8 v00, v01, v10, v11, rr;
      v00.q = *(const uint4*)(p00 + c0);
      v01.q = *(const uint4*)(p01 + c0);
      v10.q = *(const uint4*)(p10 + c0);
      v11.q = *(const uint4*)(p11 + c0);
      #pragma unroll
      for(int j=0;j<8;j++){
        rr.h[j] = (_Float16)(w00*(float)v00.h[j] + w01*(float)v01.h[j]
                           + w10*(float)v10.h[j] + w11*(float)v11.h[j]);
      }
      *(uint4*)&As[pa*40 + ca] = rr.q;
      #pragma unroll
      for(int i=0;i<BN/64;i++){
        int o = (t>>2) + i*64;
        *(uint4*)&Bs[o*40 + ca] = *(const uint4*)(wkb + (size_t)o*CIN + c0 + ca);
      }
      __syncthreads();
      f16x8 af[4];
      #pragma unroll
      for(int mi=0;mi<4;mi++)
        af[mi] = *(const f16x8*)&As[(mi*16 + l15)*40 + quad*8];
      #pragma unroll
      for(int ni=0;ni<NF;ni++){
        f16x8 bfv = *(const f16x8*)&Bs[(wave*NW + ni*16 + l15)*40 + quad*8];
        #pragma unroll
        for(int mi=0;mi<4;mi++)
          acc[mi][ni] = __builtin_amdgcn_mfma_f32_16x16x32_f16(af[mi], bfv, acc[mi][ni], 0,0,0);
      }
      __syncthreads();
    }
  }
  #pragma unroll
  for(int mi=0;mi<4;mi++){
    #pragma unroll
    for(int ni=0;ni<NF;ni++){
      int col = o0 + wave*NW + ni*16 + l15;
      float bo = bias[col];
      if(FINAL){
        float* out = (float*)outv;
        int row0 = pos0 + mi*16 + quad*4;
        int bb = row0/HWP, pr = row0%HWP;
        float4 val;
        val.x = acc[mi][ni][0]+bo; val.y = acc[mi][ni][1]+bo;
        val.z = acc[mi][ni][2]+bo; val.w = acc[mi][ni][3]+bo;
        *(float4*)(out + ((size_t)bb*COUT + col)*HWP + pr) = val;
      } else {
        _Float16* out = (_Float16*)outv;
        #pragma unroll
        for(int r=0;r<4;r++){
          int row = pos0 + mi*16 + quad*4 + r;
          out[(size_t)row*COUT + col] = (_Float16)(acc[mi][ni][r]+bo);
        }
      }
    }
  }
}

extern "C" void kernel_launch(void* const* d_in, const int* in_sizes, int n_in,
                              void* d_out, int out_size, void* d_ws, size_t ws_size,
                              hipStream_t stream){
  (void)in_sizes; (void)n_in; (void)out_size; (void)ws_size;
  const float* x   = (const float*)d_in[0];
  const float* ow1 = (const float*)d_in[1];
  const float* ob1 = (const float*)d_in[2];
  const float* w1  = (const float*)d_in[3];
  const float* b1  = (const float*)d_in[4];
  const float* ow2 = (const float*)d_in[5];
  const float* ob2 = (const float*)d_in[6];
  const float* w2  = (const float*)d_in[7];
  const float* b2  = (const float*)d_in[8];
  const float* ow3 = (const float*)d_in[9];
  const float* ob3 = (const float*)d_in[10];
  const float* w3  = (const float*)d_in[11];
  const float* b3  = (const float*)d_in[12];

  char* p = (char*)d_ws;
  auto carve = [&](size_t bytes)->char*{ char* r = p; p += (bytes + 255) & ~(size_t)255; return r; };
  _Float16* xh  = (_Float16*)carve((size_t)PTOT*64*2);
  _Float16* y1  = (_Float16*)carve((size_t)PTOT*64*2);
  _Float16* y2  = (_Float16*)carve((size_t)PTOT*512*2);
  _Float16* owT = (_Float16*)carve((size_t)9*32*512*2);
  _Float16* wT  = (_Float16*)carve((size_t)9*512*512*2);
  float*    om  = (float*)carve((size_t)PTOT*32*4);
  float*    pym = (float*)carve((size_t)PTOT*9*3*4);

  k_nchw2nhwc<<<dim3(288,2,BBATCH), dim3(32,8), 0, stream>>>(x, xh);

  // ---- layer 1: 64 -> 64 ----
  k_tow<64><<<(9*32*64+255)/256,256,0,stream>>>(ow1, owT);
  k_tw<64,64><<<(9*64*64+255)/256,256,0,stream>>>(w1, wT);
  k_goffs<64><<<PTOT/64,256,0,stream>>>(xh, owT, om);
  k_prep<<<(PTOT*9+255)/256,256,0,stream>>>(om, ob1, pym);
  k_gmain<64,64,64,0><<<dim3(PTOT/64,1),256,0,stream>>>(xh, pym, wT, b1, y1);

  // ---- layer 2: 64 -> 512 ----
  k_tow<64><<<(9*32*64+255)/256,256,0,stream>>>(ow2, owT);
  k_tw<64,512><<<(9*512*64+255)/256,256,0,stream>>>(w2, wT);
  k_goffs<64><<<PTOT/64,256,0,stream>>>(y1, owT, om);
  k_prep<<<(PTOT*9+255)/256,256,0,stream>>>(om, ob2, pym);
  k_gmain<64,512,256,0><<<dim3(PTOT/64,2),256,0,stream>>>(y1, pym, wT, b2, y2);

  // ---- layer 3: 512 -> 256 ----
  k_tow<512><<<(9*32*512+255)/256,256,0,stream>>>(ow3, owT);
  k_tw<512,256><<<(9*256*512+255)/256,256,0,stream>>>(w3, wT);
  k_goffs<512><<<PTOT/64,256,0,stream>>>(y2, owT, om);
  k_prep<<<(PTOT*9+255)/256,256,0,stream>>>(om, ob3, pym);
  k_gmain<512,256,256,1><<<dim3(PTOT/64,1),256,0,stream>>>(y2, pym, wT, b3, d_out);
}